// Round 8
// baseline (105.094 us; speedup 1.0000x reference)
//
#include <hip/hip_runtime.h>
#include <math.h>

// Canny front-end, DIRECT per-output computation (no rolling window).
// R3-R7 post-mortem: every rolling-window streaming variant sits at ~35 us
// (2.5 TB/s effective) regardless of occupancy/branches/swizzle -- the
// per-wave serial row chain + window state caps memory-level parallelism.
// Here each thread computes P=4 output rows x 4 cols straight from 30
// MUTUALLY INDEPENDENT raw-image loads (10 rows x 3 float4), dep depth 3:
// loads -> h-blur (recomputed per thread, VALU is cheap) -> v-blur -> sobel.
// Branch-free edges: clamped row addresses + multiply-mask on t rows,
// cndmask zeros on edge columns. No LDS, no barriers, no min-waves bound
// (R4: forcing low VGPR spilled 64 MB of scratch).
//
// Reference semantics: h-conv zero-pads img cols; v-conv zero-pads t rows;
// sobel zero-pads blurred rows AND cols. Output = where(mag<2, 0, mag).

#define H_IMG 1024
#define W_IMG 1024
#define W4 (W_IMG / 4)
#define P 4              // output rows per thread
#define WIN (P + 6)      // 10 raw rows in the window

__global__ __launch_bounds__(256) void canny_direct(
    const float* __restrict__ img,
    const float* __restrict__ gauss,   // 5 taps [g0,g1,g2,g1,g0]
    float* __restrict__ out)
{
    const int j   = threadIdx.x;        // float4 column 0..255 (full width)
    const int xc  = 4 * j;
    const int oy0 = blockIdx.x * P;     // first output row of this thread
    const int b   = blockIdx.y;

    const float g0 = gauss[0], g1 = gauss[1], g2 = gauss[2];
    const float* __restrict__ imgb = img + (size_t)b * (H_IMG * W_IMG);
    float* __restrict__ outb       = out + (size_t)b * (H_IMG * W_IMG);
    const float4 zero4 = make_float4(0.f, 0.f, 0.f, 0.f);

    // t[i] = h-blurred row (oy0-3+i), cols xc-1..xc+4 (zeroed if row OOB)
    float t[WIN][6];

    // Two phases of 5 rows: 15 independent loads issued per phase before any
    // consumption -> deep MLP per wave without 240-reg peak pressure.
    #pragma unroll
    for (int ph = 0; ph < 2; ++ph) {
        float4 A[5], B[5], C[5];
        #pragma unroll
        for (int i = 0; i < 5; ++i) {
            const int r  = oy0 - 3 + ph * 5 + i;
            const int rc = r < 0 ? 0 : (r > H_IMG - 1 ? H_IMG - 1 : r);   // clamped addr
            const float* p = imgb + rc * W_IMG + xc;
            A[i] = *(const float4*)(j > 0      ? p - 4 : p);
            B[i] = *(const float4*)p;
            C[i] = *(const float4*)(j < W4 - 1 ? p + 4 : p);
        }
        #pragma unroll
        for (int i = 0; i < 5; ++i) {
            const int r = oy0 - 3 + ph * 5 + i;
            const float m = (r >= 0 && r < H_IMG) ? 1.0f : 0.0f;  // v-conv zero-pad of t rows
            float4 Ai = A[i], Bi = B[i], Ci = C[i];
            if (j == 0)      Ai = zero4;    // h-conv zero-pad of img cols
            if (j == W4 - 1) Ci = zero4;
            float* h = t[ph * 5 + i];
            h[0] = m * (g0 * (Ai.y + Bi.y) + g1 * (Ai.z + Bi.x) + g2 * Ai.w); // col xc-1
            h[1] = m * (g0 * (Ai.z + Bi.z) + g1 * (Ai.w + Bi.y) + g2 * Bi.x); // col xc
            h[2] = m * (g0 * (Ai.w + Bi.w) + g1 * (Bi.x + Bi.z) + g2 * Bi.y); // col xc+1
            h[3] = m * (g0 * (Bi.x + Ci.x) + g1 * (Bi.y + Bi.w) + g2 * Bi.z); // col xc+2
            h[4] = m * (g0 * (Bi.y + Ci.y) + g1 * (Bi.z + Ci.x) + g2 * Bi.w); // col xc+3
            h[5] = m * (g0 * (Bi.z + Ci.z) + g1 * (Bi.w + Ci.y) + g2 * Ci.x); // col xc+4
        }
    }

    // bl[k] = fully blurred row (oy0-1+k), k=0..P+1; zeroed if row OOB
    // (sobel's zero-pad of blurred rows); edge cols zeroed (sobel col pad).
    float bl[P + 2][6];
    #pragma unroll
    for (int k = 0; k < P + 2; ++k) {
        const int r = oy0 - 1 + k;
        const float m = (r >= 0 && r < H_IMG) ? 1.0f : 0.0f;
        #pragma unroll
        for (int c = 0; c < 6; ++c)
            bl[k][c] = m * (g0 * (t[k][c] + t[k + 4][c])
                          + g1 * (t[k + 1][c] + t[k + 3][c])
                          + g2 *  t[k + 2][c]);
        if (j == 0)      bl[k][0] = 0.0f;   // blurred col -1
        if (j == W4 - 1) bl[k][5] = 0.0f;   // blurred col 1024
    }

    // sobel + magnitude + threshold, 4 output rows, float4 stores
    #pragma unroll
    for (int mrow = 0; mrow < P; ++mrow) {
        const float* T  = bl[mrow];         // blurred(oy-1)
        const float* M  = bl[mrow + 1];     // blurred(oy)
        const float* Bo = bl[mrow + 2];     // blurred(oy+1)
        float4 o4;
        float* po = (float*)&o4;
        #pragma unroll
        for (int k = 0; k < 4; ++k) {
            float gx = (T[k] - T[k + 2]) + 2.0f * (M[k] - M[k + 2]) + (Bo[k] - Bo[k + 2]);
            float gy = (T[k] + 2.0f * T[k + 1] + T[k + 2])
                     - (Bo[k] + 2.0f * Bo[k + 1] + Bo[k + 2]);
            float mag = sqrtf(gx * gx + gy * gy);
            po[k] = (mag < 2.0f) ? 0.0f : mag;
        }
        *(float4*)(outb + (oy0 + mrow) * W_IMG + xc) = o4;
    }
}

extern "C" void kernel_launch(void* const* d_in, const int* in_sizes, int n_in,
                              void* d_out, int out_size, void* d_ws, size_t ws_size,
                              hipStream_t stream) {
    const float* img   = (const float*)d_in[0];
    const float* gauss = (const float*)d_in[1];
    float* out = (float*)d_out;
    const int N = in_sizes[0] / (H_IMG * W_IMG);   // = 8

    dim3 grid(H_IMG / P, N);                       // (256, 8) = 2048 blocks
    canny_direct<<<grid, 256, 0, stream>>>(img, gauss, out);
}